// Round 10
// baseline (111.409 us; speedup 1.0000x reference)
//
#include <hip/hip_runtime.h>
#include <hip/hip_fp16.h>
#include <math.h>

// ---------------------------------------------------------------------------
// SuperCKAN forward:
//   conv1 (k=5, grid5, n=12)  + pool -> (256,12,12,12)
//   conv2 (k=4, grid10, n=12) + pool -> (256,144,4,4)
//   conv3 (k=3, grid10, n=24) + pool -> (256,3456)
//   fc: x @ (w2@w1)^T + (b1@w2^T + b2) -> (256,10)
//
// R9: REVERT R8's dy-split (occupancy was not the limit; LDS pipe per-CU was
// already saturated -> doubling waves only doubled staging+sync: 66.8->77.8).
// Back to R5's 4-lane structure. f16 weight tables RETRY, this time with
// macro-expanded fully-inline row FMA (R7 regressed because row_fma took
// float* acc -> SROA defeated -> acc in scratch -> 38MB FETCH/conv).
// LDS reads/element: 15 -> 10 (N=12), 30 -> 15 (N=24); bytes halved.
// Accumulation fp32; f16 numerics verified in R7 (absmax 9.8e-4 < 5.2e-3).
// R4/R5 design kept: zero-padded tables [base][4 pad][G][4 pad], s clamped
// to [-1,NINT] (boundaries hit pad rows, no masking); strided prep; f4 fc.
// ---------------------------------------------------------------------------

#define B_BATCH 256

// Weight layout per layer: [K*K][R][NP] halves, R = G+9:
//   row 0: base (silu) w; rows 1..4: zero pad; rows 5..G+4: spline g=0..G-1
//   (scaler folded); rows G+5..G+8: zero pad. Cols N..NP-1 zero.
// Spline rows for interval t (clamped to [-1,NINT]) are t+2+m, m=0..3.

__device__ __forceinline__ float2 h2f(unsigned v)
{
    union { unsigned u; __half2 h; } cv; cv.u = v;
    return __half22float2(cv.h);
}

// N=12 row: 1x uint4 (8 halves) + 1x uint2 (4 halves); acc literal-indexed.
#define ROW_FMA12(rowptr, cf) do {                                          \
    uint4 _u = *(const uint4*)(rowptr);                                     \
    uint2 _v = *(const uint2*)((const __half*)(rowptr) + 8);                \
    float2 _f;                                                              \
    _f = h2f(_u.x); acc[0] = fmaf(cf, _f.x, acc[0]);  acc[1] = fmaf(cf, _f.y, acc[1]);   \
    _f = h2f(_u.y); acc[2] = fmaf(cf, _f.x, acc[2]);  acc[3] = fmaf(cf, _f.y, acc[3]);   \
    _f = h2f(_u.z); acc[4] = fmaf(cf, _f.x, acc[4]);  acc[5] = fmaf(cf, _f.y, acc[5]);   \
    _f = h2f(_u.w); acc[6] = fmaf(cf, _f.x, acc[6]);  acc[7] = fmaf(cf, _f.y, acc[7]);   \
    _f = h2f(_v.x); acc[8] = fmaf(cf, _f.x, acc[8]);  acc[9] = fmaf(cf, _f.y, acc[9]);   \
    _f = h2f(_v.y); acc[10] = fmaf(cf, _f.x, acc[10]); acc[11] = fmaf(cf, _f.y, acc[11]); \
} while (0)

// N=24 row: 3x uint4.
#define ROW_FMA24(rowptr, cf) do {                                          \
    uint4 _a = *(const uint4*)(rowptr);                                     \
    uint4 _b = *(const uint4*)((const __half*)(rowptr) + 8);                \
    uint4 _c = *(const uint4*)((const __half*)(rowptr) + 16);               \
    float2 _f;                                                              \
    _f = h2f(_a.x); acc[0] = fmaf(cf, _f.x, acc[0]);  acc[1] = fmaf(cf, _f.y, acc[1]);   \
    _f = h2f(_a.y); acc[2] = fmaf(cf, _f.x, acc[2]);  acc[3] = fmaf(cf, _f.y, acc[3]);   \
    _f = h2f(_a.z); acc[4] = fmaf(cf, _f.x, acc[4]);  acc[5] = fmaf(cf, _f.y, acc[5]);   \
    _f = h2f(_a.w); acc[6] = fmaf(cf, _f.x, acc[6]);  acc[7] = fmaf(cf, _f.y, acc[7]);   \
    _f = h2f(_b.x); acc[8] = fmaf(cf, _f.x, acc[8]);  acc[9] = fmaf(cf, _f.y, acc[9]);   \
    _f = h2f(_b.y); acc[10] = fmaf(cf, _f.x, acc[10]); acc[11] = fmaf(cf, _f.y, acc[11]); \
    _f = h2f(_b.z); acc[12] = fmaf(cf, _f.x, acc[12]); acc[13] = fmaf(cf, _f.y, acc[13]); \
    _f = h2f(_b.w); acc[14] = fmaf(cf, _f.x, acc[14]); acc[15] = fmaf(cf, _f.y, acc[15]); \
    _f = h2f(_c.x); acc[16] = fmaf(cf, _f.x, acc[16]); acc[17] = fmaf(cf, _f.y, acc[17]); \
    _f = h2f(_c.y); acc[18] = fmaf(cf, _f.x, acc[18]); acc[19] = fmaf(cf, _f.y, acc[19]); \
    _f = h2f(_c.z); acc[20] = fmaf(cf, _f.x, acc[20]); acc[21] = fmaf(cf, _f.y, acc[21]); \
    _f = h2f(_c.w); acc[22] = fmaf(cf, _f.x, acc[22]); acc[23] = fmaf(cf, _f.y, acc[23]); \
} while (0)

// ---- unified prep kernel ---------------------------------------------------
// block 0: W1m   block 1: W2m   block 2: W3m   block 3: bf   blocks 4..138: Wf
__global__ __launch_bounds__(256) void prep_all(
    const float* __restrict__ bw1, const float* __restrict__ sw1, const float* __restrict__ sc1,
    const float* __restrict__ bw2, const float* __restrict__ sw2, const float* __restrict__ sc2,
    const float* __restrict__ bw3, const float* __restrict__ sw3, const float* __restrict__ sc3,
    const float* __restrict__ b1, const float* __restrict__ w2, const float* __restrict__ b2,
    const float* __restrict__ w1,
    __half* __restrict__ W1m, __half* __restrict__ W2m, __half* __restrict__ W3m,
    float* __restrict__ bf, float* __restrict__ Wf)
{
    int blk = blockIdx.x;
    int tid = threadIdx.x;
    if (blk == 0) {                      // layer1: 300 entries, R=17, NP=16, G=8
        for (int i = tid; i < 25 * 17 * 16; i += 256) W1m[i] = __float2half(0.f);
        __syncthreads();
        for (int e = tid; e < 300; e += 256) {
            int n = e / 25, k = e % 25;
            float sc = sc1[n * 25 + k];
            W1m[(k * 17 + 0) * 16 + n] = __float2half(bw1[n * 25 + k]);
            for (int g = 0; g < 8; ++g)
                W1m[(k * 17 + 5 + g) * 16 + n] = __float2half(sw1[(n * 25 + k) * 8 + g] * sc);
        }
    } else if (blk == 1) {               // layer2: 192 entries, R=22, NP=16, G=13
        for (int i = tid; i < 16 * 22 * 16; i += 256) W2m[i] = __float2half(0.f);
        __syncthreads();
        for (int e = tid; e < 192; e += 256) {
            int n = e / 16, k = e % 16;
            float sc = sc2[n * 16 + k];
            W2m[(k * 22 + 0) * 16 + n] = __float2half(bw2[n * 16 + k]);
            for (int g = 0; g < 13; ++g)
                W2m[(k * 22 + 5 + g) * 16 + n] = __float2half(sw2[(n * 16 + k) * 13 + g] * sc);
        }
    } else if (blk == 2) {               // layer3: 216 entries, R=22, NP=24, G=13
        for (int i = tid; i < 9 * 22 * 24; i += 256) W3m[i] = __float2half(0.f);
        __syncthreads();
        for (int e = tid; e < 216; e += 256) {
            int n = e / 9, k = e % 9;
            float sc = sc3[n * 9 + k];
            W3m[(k * 22 + 0) * 24 + n] = __float2half(bw3[n * 9 + k]);
            for (int g = 0; g < 13; ++g)
                W3m[(k * 22 + 5 + g) * 24 + n] = __float2half(sw3[(n * 9 + k) * 13 + g] * sc);
        }
    } else if (blk == 3) {               // folded bias (first wave only)
        if (tid < 64) {
            int lane = tid;
            for (int n = 0; n < 10; ++n) {
                float s = 0.f;
                for (int j = lane; j < 256; j += 64) s = fmaf(b1[j], w2[n * 256 + j], s);
                for (int o = 32; o; o >>= 1) s += __shfl_down(s, o, 64);
                if (lane == 0) bf[n] = s + b2[n];
            }
        }
    } else {                             // Wf = w2 @ w1 (10 x 3456)
        int gid = (blk - 4) * 256 + tid; // 135*256 = 34560 exact
        int n = gid / 3456, m = gid % 3456;
        float s = 0.f;
        for (int j = 0; j < 256; ++j)
            s = fmaf(w2[n * 256 + j], w1[j * 3456 + m], s);
        Wf[n * 3456 + m] = s;
    }
}

// ---- fused KAN conv + 2x2 maxpool, sparse spline, inline-f16 weights ------
// Thread quad (4 lanes, sub = 2x2 conv position) per pooled output position.
// Grid is EXACT (B_BATCH*C*POS*4 threads): no early return.
template <int K, int NINT, int G, int N, int NP, int C, int HIN, int WIN,
          int HP, int WP>
__global__ __launch_bounds__(256, 4) void kan_conv_pool(
    const float* __restrict__ in, const __half* __restrict__ W,
    float* __restrict__ out, float g0, float invh)
{
    constexpr int R = G + 9;
    constexpr int POS = HP * WP;
    constexpr int WSZ = K * K * R * NP;        // halves, multiple of 8
    static_assert((WSZ % 8) == 0 && (N == 12 || N == 24), "layout");

    __shared__ __half sw[WSZ];
    for (int i = threadIdx.x; i < WSZ / 8; i += 256)
        reinterpret_cast<uint4*>(sw)[i] = reinterpret_cast<const uint4*>(W)[i];
    __syncthreads();

    int tid = blockIdx.x * 256 + threadIdx.x;

    int sub = tid & 3;
    int rem = tid >> 2;
    int pos = rem % POS;
    int bc  = rem / POS;               // b*C + c
    int pi = pos / WP, pj = pos % WP;
    int p = 2 * pi + (sub >> 1);
    int q = 2 * pj + (sub & 1);

    const float* inp = in + bc * (HIN * WIN);

    float acc[N];
#pragma unroll
    for (int n = 0; n < N; ++n) acc[n] = 0.f;

#pragma unroll 1
    for (int dy = 0; dy < K; ++dy) {
#pragma unroll
        for (int dx = 0; dx < K; ++dx) {
            float v = inp[(p + dy) * WIN + (q + dx)];

            float s  = (v - g0) * invh;
            float sc = fminf(fmaxf(s, -1.0f), (float)NINT);  // sentinels hit pads
            float sf = floorf(sc);
            int   t  = (int)sf;
            float u  = sc - sf;                 // in [0,1]: coeffs stay finite
            float u2 = u * u, u3 = u2 * u;
            float um = 1.0f - u;
            float c0 = um * um * um * (1.0f / 6.0f);
            float c1 = (3.0f * u3 - 6.0f * u2 + 4.0f) * (1.0f / 6.0f);
            float c2 = (-3.0f * u3 + 3.0f * u2 + 3.0f * u + 1.0f) * (1.0f / 6.0f);
            float c3 = u3 * (1.0f / 6.0f);
            float sv = v / (1.0f + __expf(-v)); // silu

            const __half* wk = sw + (dy * K + dx) * (R * NP); // base row
            const __half* wt = wk + (t + 2) * NP;             // spline rows

            if constexpr (N == 12) {
                ROW_FMA12(wk,          sv);
                ROW_FMA12(wt + 0 * NP, c0);
                ROW_FMA12(wt + 1 * NP, c1);
                ROW_FMA12(wt + 2 * NP, c2);
                ROW_FMA12(wt + 3 * NP, c3);
            } else {
                ROW_FMA24(wk,          sv);
                ROW_FMA24(wt + 0 * NP, c0);
                ROW_FMA24(wt + 1 * NP, c1);
                ROW_FMA24(wt + 2 * NP, c2);
                ROW_FMA24(wt + 3 * NP, c3);
            }
        }
    }

    // 2x2 maxpool across the lane quad
#pragma unroll
    for (int n = 0; n < N; ++n) {
        acc[n] = fmaxf(acc[n], __shfl_xor(acc[n], 1, 64));
        acc[n] = fmaxf(acc[n], __shfl_xor(acc[n], 2, 64));
    }

    // each of the 4 lanes writes N/4 channels
    constexpr int NPL = N / 4;
    int n0 = sub * NPL;
    float* op = out + bc * (N * POS) + pos;
#pragma unroll
    for (int i = 0; i < NPL; ++i)
        op[(n0 + i) * POS] = acc[n0 + i];
}

// ---- final GEMV: out = x3 @ Wf^T + bf; grid 2560 waves exact --------------
__global__ __launch_bounds__(256) void fc_kernel(
    const float* __restrict__ x3, const float* __restrict__ Wf,
    const float* __restrict__ bf, float* __restrict__ out)
{
    int wid  = (blockIdx.x * 256 + threadIdx.x) >> 6;
    int lane = threadIdx.x & 63;
    int b = wid / 10, n = wid - b * 10;
    const float4* xr = (const float4*)(x3 + b * 3456);
    const float4* wr = (const float4*)(Wf + n * 3456);
    float s = 0.f;
#pragma unroll
    for (int i = 0; i < 13; ++i) {       // 13*64*4 = 3328 floats
        float4 a = xr[lane + i * 64];
        float4 w = wr[lane + i * 64];
        s = fmaf(a.x, w.x, s); s = fmaf(a.y, w.y, s);
        s = fmaf(a.z, w.z, s); s = fmaf(a.w, w.w, s);
    }
    const float* xs = x3 + b * 3456 + 3328;   // remainder 128 floats
    const float* wsp = Wf + n * 3456 + 3328;
    s = fmaf(xs[lane], wsp[lane], s);
    s = fmaf(xs[lane + 64], wsp[lane + 64], s);
    for (int o = 32; o; o >>= 1) s += __shfl_down(s, o, 64);
    if (lane == 0) out[wid] = s + bf[n];
}

// ---------------------------------------------------------------------------
extern "C" void kernel_launch(void* const* d_in, const int* in_sizes, int n_in,
                              void* d_out, int out_size, void* d_ws, size_t ws_size,
                              hipStream_t stream)
{
    (void)in_sizes; (void)n_in; (void)out_size; (void)ws_size;
    const float* x   = (const float*)d_in[0];
    const float* bw1 = (const float*)d_in[1];
    const float* sw1 = (const float*)d_in[2];
    const float* sc1 = (const float*)d_in[3];
    const float* bw2 = (const float*)d_in[4];
    const float* sw2 = (const float*)d_in[5];
    const float* sc2 = (const float*)d_in[6];
    const float* bw3 = (const float*)d_in[7];
    const float* sw3 = (const float*)d_in[8];
    const float* sc3 = (const float*)d_in[9];
    const float* w1  = (const float*)d_in[10];
    const float* b1  = (const float*)d_in[11];
    const float* w2  = (const float*)d_in[12];
    const float* b2  = (const float*)d_in[13];

    float* ws  = (float*)d_ws;
    // f16 tables (halves -> floats/2): W1m 6800h=3400f, W2m 5632h=2816f,
    // W3m 4752h=2376f
    __half* W1m = (__half*)(ws);           // floats [0, 3400)
    __half* W2m = (__half*)(ws + 3400);    // floats [3400, 6216)
    __half* W3m = (__half*)(ws + 6216);    // floats [6216, 8592)
    float*  bf  = ws + 8592;               // 10 (+pad)
    float*  Wf  = ws + 8640;               // 34560
    float*  o1  = ws + 43200;              // 256*12*12*12 = 442368
    float*  o2  = ws + 485568;             // 256*144*4*4  = 589824
    float*  x3  = ws + 1075392;            // 256*3456     = 884736
    float*  out = (float*)d_out;

    prep_all<<<139, 256, 0, stream>>>(bw1, sw1, sc1, bw2, sw2, sc2,
                                      bw3, sw3, sc3, b1, w2, b2, w1,
                                      W1m, W2m, W3m, bf, Wf);

    const float h1 = 2.0f / 5.0f, h2 = 2.0f / 10.0f;
    // layer1: K=5, NINT=11, G=8,  N=12, NP=16, C=1,   28x28 -> pooled 12x12
    kan_conv_pool<5, 11, 8, 12, 16, 1, 28, 28, 12, 12>
        <<<576, 256, 0, stream>>>(x, W1m, o1, -3.0f * h1 - 1.0f, 1.0f / h1);
    // layer2: K=4, NINT=16, G=13, N=12, NP=16, C=12,  12x12 -> pooled 4x4
    kan_conv_pool<4, 16, 13, 12, 16, 12, 12, 12, 4, 4>
        <<<768, 256, 0, stream>>>(o1, W2m, o2, -3.0f * h2 - 1.0f, 1.0f / h2);
    // layer3: K=3, NINT=16, G=13, N=24, NP=24, C=144, 4x4  -> pooled 1x1
    kan_conv_pool<3, 16, 13, 24, 24, 144, 4, 4, 1, 1>
        <<<576, 256, 0, stream>>>(o2, W3m, x3, -3.0f * h2 - 1.0f, 1.0f / h2);

    fc_kernel<<<640, 256, 0, stream>>>(x3, Wf, bf, out);
}

// Round 11
// 80.427 us; speedup vs baseline: 1.3852x; 1.3852x over previous
//
#include <hip/hip_runtime.h>
#include <hip/hip_fp16.h>
#include <math.h>

// ---------------------------------------------------------------------------
// SuperCKAN forward:
//   conv1 (k=5, grid5, n=12)  + pool -> (256,12,12,12)
//   conv2 (k=4, grid10, n=12) + pool -> (256,144,4,4)
//   conv3 (k=3, grid10, n=24) + pool -> (256,3456)
//   fc: x @ (w2@w1)^T + (b1@w2^T + b2) -> (256,10)
//
// R10: hedged f16. Both f16 attempts (R7/R9) showed scratch-class traffic on
// the conv3 dispatch (LDS 9728B). This round: conv3 stays EXACT R5 fp32;
// conv1/conv2 use f16 weights PACKED INSIDE float-typed LDS (reads are
// float4/float2 -- identical instruction shape to the working R5 kernel),
// unpacked with __ushort_as_half/__half2float on named scalars. No unions,
// no __half-typed LDS, no uint4 punning, acc literal-indexed only.
// Packed row = 8 floats (=16 halves: 12 channels + 4 pad), 32B-aligned.
// LDS instrs/element conv1/2: 15 -> 10; bytes halved on those layers.
// R4/R5 design kept: zero-padded tables [base][4 pad][G][4 pad], s clamped
// to [-1,NINT]; strided prep; unified prep kernel; float4 fc GEMV.
// ---------------------------------------------------------------------------

#define B_BATCH 256

// unpack one packed half-pair (inside a float) -> 2 fp32, fma into acc
#define PFMA(pf, cf, i0) do {                                                \
    unsigned _u = __float_as_uint(pf);                                       \
    float _lo = __half2float(__ushort_as_half((unsigned short)(_u & 0xffffu)));\
    float _hi = __half2float(__ushort_as_half((unsigned short)(_u >> 16)));  \
    acc[(i0)]     = fmaf(cf, _lo, acc[(i0)]);                                \
    acc[(i0) + 1] = fmaf(cf, _hi, acc[(i0) + 1]);                            \
} while (0)

// one packed row (12 channels in 6 floats, +2 pad floats) scaled by cf
#define ROWP12(rowptr, cf) do {                                              \
    float4 _a = *(const float4*)(rowptr);                                    \
    float2 _b = *(const float2*)((rowptr) + 4);                              \
    PFMA(_a.x, cf, 0); PFMA(_a.y, cf, 2); PFMA(_a.z, cf, 4);                 \
    PFMA(_a.w, cf, 6); PFMA(_b.x, cf, 8); PFMA(_b.y, cf, 10);                \
} while (0)

// ---- unified prep kernel ---------------------------------------------------
// block 0: W1h   block 1: W2h   block 2: W3m(fp32)   block 3: bf
// blocks 4..138: Wf
__global__ __launch_bounds__(256) void prep_all(
    const float* __restrict__ bw1, const float* __restrict__ sw1, const float* __restrict__ sc1,
    const float* __restrict__ bw2, const float* __restrict__ sw2, const float* __restrict__ sc2,
    const float* __restrict__ bw3, const float* __restrict__ sw3, const float* __restrict__ sc3,
    const float* __restrict__ b1, const float* __restrict__ w2, const float* __restrict__ b2,
    const float* __restrict__ w1,
    float* __restrict__ W1h, float* __restrict__ W2h, float* __restrict__ W3m,
    float* __restrict__ bf, float* __restrict__ Wf)
{
    int blk = blockIdx.x;
    int tid = threadIdx.x;
    if (blk == 0) {                      // layer1 packed: 25*17 rows * 8 floats
        for (int i = tid; i < 25 * 17 * 8; i += 256) W1h[i] = 0.f;
        __syncthreads();
        unsigned short* W1u = (unsigned short*)W1h;
        for (int e = tid; e < 300; e += 256) {
            int n = e / 25, k = e % 25;
            float sc = sc1[n * 25 + k];
            // ushort index of (k, r, channel n): ((k*17 + r)*8 + n/2)*2 + (n&1)
            W1u[((k * 17 + 0) * 8 + (n >> 1)) * 2 + (n & 1)] =
                __half_as_ushort(__float2half(bw1[n * 25 + k]));
            for (int g = 0; g < 8; ++g)
                W1u[((k * 17 + 5 + g) * 8 + (n >> 1)) * 2 + (n & 1)] =
                    __half_as_ushort(__float2half(sw1[(n * 25 + k) * 8 + g] * sc));
        }
    } else if (blk == 1) {               // layer2 packed: 16*22 rows * 8 floats
        for (int i = tid; i < 16 * 22 * 8; i += 256) W2h[i] = 0.f;
        __syncthreads();
        unsigned short* W2u = (unsigned short*)W2h;
        for (int e = tid; e < 192; e += 256) {
            int n = e / 16, k = e % 16;
            float sc = sc2[n * 16 + k];
            W2u[((k * 22 + 0) * 8 + (n >> 1)) * 2 + (n & 1)] =
                __half_as_ushort(__float2half(bw2[n * 16 + k]));
            for (int g = 0; g < 13; ++g)
                W2u[((k * 22 + 5 + g) * 8 + (n >> 1)) * 2 + (n & 1)] =
                    __half_as_ushort(__float2half(sw2[(n * 16 + k) * 13 + g] * sc));
        }
    } else if (blk == 2) {               // layer3 fp32 (exact R5): 9*22*24
        for (int i = tid; i < 9 * 22 * 24; i += 256) W3m[i] = 0.f;
        __syncthreads();
        for (int e = tid; e < 216; e += 256) {
            int n = e / 9, k = e % 9;
            float sc = sc3[n * 9 + k];
            W3m[(k * 22 + 0) * 24 + n] = bw3[n * 9 + k];
            for (int g = 0; g < 13; ++g)
                W3m[(k * 22 + 5 + g) * 24 + n] = sw3[(n * 9 + k) * 13 + g] * sc;
        }
    } else if (blk == 3) {               // folded bias (first wave only)
        if (tid < 64) {
            int lane = tid;
            for (int n = 0; n < 10; ++n) {
                float s = 0.f;
                for (int j = lane; j < 256; j += 64) s = fmaf(b1[j], w2[n * 256 + j], s);
                for (int o = 32; o; o >>= 1) s += __shfl_down(s, o, 64);
                if (lane == 0) bf[n] = s + b2[n];
            }
        }
    } else {                             // Wf = w2 @ w1 (10 x 3456)
        int gid = (blk - 4) * 256 + tid; // 135*256 = 34560 exact
        int n = gid / 3456, m = gid % 3456;
        float s = 0.f;
        for (int j = 0; j < 256; ++j)
            s = fmaf(w2[n * 256 + j], w1[j * 3456 + m], s);
        Wf[n * 3456 + m] = s;
    }
}

// ---- fused KAN conv + 2x2 maxpool, packed-f16 weights (N=12 only) ---------
// Thread quad (4 lanes, sub = 2x2 conv position) per pooled output position.
// Grid is EXACT (B_BATCH*C*POS*4 threads): no early return.
// Table: [K*K][R][8] floats, each float = 2 packed halves (12 ch + 4 pad).
template <int K, int NINT, int G, int C, int HIN, int WIN, int HP, int WP>
__global__ __launch_bounds__(256, 4) void kan_conv_pool_h(
    const float* __restrict__ in, const float* __restrict__ W,
    float* __restrict__ out, float g0, float invh)
{
    constexpr int N = 12;
    constexpr int R = G + 9;
    constexpr int POS = HP * WP;
    constexpr int WSZ = K * K * R * 8;         // floats

    __shared__ float sw[WSZ];
    for (int i = threadIdx.x; i < WSZ; i += 256) sw[i] = W[i];
    __syncthreads();

    int tid = blockIdx.x * 256 + threadIdx.x;

    int sub = tid & 3;
    int rem = tid >> 2;
    int pos = rem % POS;
    int bc  = rem / POS;               // b*C + c
    int pi = pos / WP, pj = pos % WP;
    int p = 2 * pi + (sub >> 1);
    int q = 2 * pj + (sub & 1);

    const float* inp = in + bc * (HIN * WIN);

    float acc[N];
#pragma unroll
    for (int n = 0; n < N; ++n) acc[n] = 0.f;

#pragma unroll 1
    for (int dy = 0; dy < K; ++dy) {
#pragma unroll
        for (int dx = 0; dx < K; ++dx) {
            float v = inp[(p + dy) * WIN + (q + dx)];

            float s  = (v - g0) * invh;
            float sc = fminf(fmaxf(s, -1.0f), (float)NINT);  // sentinels hit pads
            float sf = floorf(sc);
            int   t  = (int)sf;
            float u  = sc - sf;                 // in [0,1]: coeffs stay finite
            float u2 = u * u, u3 = u2 * u;
            float um = 1.0f - u;
            float c0 = um * um * um * (1.0f / 6.0f);
            float c1 = (3.0f * u3 - 6.0f * u2 + 4.0f) * (1.0f / 6.0f);
            float c2 = (-3.0f * u3 + 3.0f * u2 + 3.0f * u + 1.0f) * (1.0f / 6.0f);
            float c3 = u3 * (1.0f / 6.0f);
            float sv = v / (1.0f + __expf(-v)); // silu

            const float* wk = sw + (dy * K + dx) * (R * 8);  // base row
            const float* wt = wk + (t + 2) * 8;              // spline rows

            ROWP12(wk,         sv);
            ROWP12(wt + 0 * 8, c0);
            ROWP12(wt + 1 * 8, c1);
            ROWP12(wt + 2 * 8, c2);
            ROWP12(wt + 3 * 8, c3);
        }
    }

    // 2x2 maxpool across the lane quad
#pragma unroll
    for (int n = 0; n < N; ++n) {
        acc[n] = fmaxf(acc[n], __shfl_xor(acc[n], 1, 64));
        acc[n] = fmaxf(acc[n], __shfl_xor(acc[n], 2, 64));
    }

    constexpr int NPL = N / 4;
    int n0 = sub * NPL;
    float* op = out + bc * (N * POS) + pos;
#pragma unroll
    for (int i = 0; i < NPL; ++i)
        op[(n0 + i) * POS] = acc[n0 + i];
}

// ---- fused KAN conv + 2x2 maxpool, fp32 (EXACT R5; used for conv3) --------
template <int K, int NINT, int G, int N, int C, int HIN, int WIN, int HP, int WP>
__global__ __launch_bounds__(256, 4) void kan_conv_pool(
    const float* __restrict__ in, const float* __restrict__ W,
    float* __restrict__ out, float g0, float invh)
{
    constexpr int R = G + 9;
    constexpr int POS = HP * WP;
    constexpr int WSZ = K * K * R * N;
    static_assert((N % 4) == 0, "alignment");

    __shared__ float sw[WSZ];
    for (int i = threadIdx.x; i < WSZ; i += 256) sw[i] = W[i];
    __syncthreads();

    int tid = blockIdx.x * 256 + threadIdx.x;

    int sub = tid & 3;
    int rem = tid >> 2;
    int pos = rem % POS;
    int bc  = rem / POS;               // b*C + c
    int pi = pos / WP, pj = pos % WP;
    int p = 2 * pi + (sub >> 1);
    int q = 2 * pj + (sub & 1);

    const float* inp = in + bc * (HIN * WIN);

    float acc[N];
#pragma unroll
    for (int n = 0; n < N; ++n) acc[n] = 0.f;

#pragma unroll 1
    for (int dy = 0; dy < K; ++dy) {
#pragma unroll
        for (int dx = 0; dx < K; ++dx) {
            float v = inp[(p + dy) * WIN + (q + dx)];

            float s  = (v - g0) * invh;
            float sc = fminf(fmaxf(s, -1.0f), (float)NINT);  // sentinels hit pads
            float sf = floorf(sc);
            int   t  = (int)sf;
            float u  = sc - sf;                 // in [0,1]: coeffs stay finite
            float u2 = u * u, u3 = u2 * u;
            float um = 1.0f - u;
            float c0 = um * um * um * (1.0f / 6.0f);
            float c1 = (3.0f * u3 - 6.0f * u2 + 4.0f) * (1.0f / 6.0f);
            float c2 = (-3.0f * u3 + 3.0f * u2 + 3.0f * u + 1.0f) * (1.0f / 6.0f);
            float c3 = u3 * (1.0f / 6.0f);
            float sv = v / (1.0f + __expf(-v)); // silu

            const float* wk = sw + (dy * K + dx) * (R * N);  // base row (uniform)
            const float* wt = wk + (t + 2) * N;              // spline row block

#pragma unroll
            for (int n4 = 0; n4 < N / 4; ++n4) {
                float4 wb = ((const float4*)wk)[n4];
                float4 w0 = ((const float4*)(wt + 0 * N))[n4];
                float4 w1_ = ((const float4*)(wt + 1 * N))[n4];
                float4 w2_ = ((const float4*)(wt + 2 * N))[n4];
                float4 w3_ = ((const float4*)(wt + 3 * N))[n4];
                float a0 = acc[n4 * 4 + 0], a1 = acc[n4 * 4 + 1];
                float a2 = acc[n4 * 4 + 2], a3 = acc[n4 * 4 + 3];
                a0 = fmaf(sv, wb.x, a0); a1 = fmaf(sv, wb.y, a1);
                a2 = fmaf(sv, wb.z, a2); a3 = fmaf(sv, wb.w, a3);
                a0 = fmaf(c0, w0.x, a0); a1 = fmaf(c0, w0.y, a1);
                a2 = fmaf(c0, w0.z, a2); a3 = fmaf(c0, w0.w, a3);
                a0 = fmaf(c1, w1_.x, a0); a1 = fmaf(c1, w1_.y, a1);
                a2 = fmaf(c1, w1_.z, a2); a3 = fmaf(c1, w1_.w, a3);
                a0 = fmaf(c2, w2_.x, a0); a1 = fmaf(c2, w2_.y, a1);
                a2 = fmaf(c2, w2_.z, a2); a3 = fmaf(c2, w2_.w, a3);
                a0 = fmaf(c3, w3_.x, a0); a1 = fmaf(c3, w3_.y, a1);
                a2 = fmaf(c3, w3_.z, a2); a3 = fmaf(c3, w3_.w, a3);
                acc[n4 * 4 + 0] = a0; acc[n4 * 4 + 1] = a1;
                acc[n4 * 4 + 2] = a2; acc[n4 * 4 + 3] = a3;
            }
        }
    }

    // 2x2 maxpool across the lane quad
#pragma unroll
    for (int n = 0; n < N; ++n) {
        acc[n] = fmaxf(acc[n], __shfl_xor(acc[n], 1, 64));
        acc[n] = fmaxf(acc[n], __shfl_xor(acc[n], 2, 64));
    }

    constexpr int NPL = N / 4;
    int n0 = sub * NPL;
    float* op = out + bc * (N * POS) + pos;
#pragma unroll
    for (int i = 0; i < NPL; ++i)
        op[(n0 + i) * POS] = acc[n0 + i];
}

// ---- final GEMV: out = x3 @ Wf^T + bf; grid 2560 waves exact --------------
__global__ __launch_bounds__(256) void fc_kernel(
    const float* __restrict__ x3, const float* __restrict__ Wf,
    const float* __restrict__ bf, float* __restrict__ out)
{
    int wid  = (blockIdx.x * 256 + threadIdx.x) >> 6;
    int lane = threadIdx.x & 63;
    int b = wid / 10, n = wid - b * 10;
    const float4* xr = (const float4*)(x3 + b * 3456);
    const float4* wr = (const float4*)(Wf + n * 3456);
    float s = 0.f;
#pragma unroll
    for (int i = 0; i < 13; ++i) {       // 13*64*4 = 3328 floats
        float4 a = xr[lane + i * 64];
        float4 w = wr[lane + i * 64];
        s = fmaf(a.x, w.x, s); s = fmaf(a.y, w.y, s);
        s = fmaf(a.z, w.z, s); s = fmaf(a.w, w.w, s);
    }
    const float* xs = x3 + b * 3456 + 3328;   // remainder 128 floats
    const float* wsp = Wf + n * 3456 + 3328;
    s = fmaf(xs[lane], wsp[lane], s);
    s = fmaf(xs[lane + 64], wsp[lane + 64], s);
    for (int o = 32; o; o >>= 1) s += __shfl_down(s, o, 64);
    if (lane == 0) out[wid] = s + bf[n];
}

// ---------------------------------------------------------------------------
extern "C" void kernel_launch(void* const* d_in, const int* in_sizes, int n_in,
                              void* d_out, int out_size, void* d_ws, size_t ws_size,
                              hipStream_t stream)
{
    (void)in_sizes; (void)n_in; (void)out_size; (void)ws_size;
    const float* x   = (const float*)d_in[0];
    const float* bw1 = (const float*)d_in[1];
    const float* sw1 = (const float*)d_in[2];
    const float* sc1 = (const float*)d_in[3];
    const float* bw2 = (const float*)d_in[4];
    const float* sw2 = (const float*)d_in[5];
    const float* sc2 = (const float*)d_in[6];
    const float* bw3 = (const float*)d_in[7];
    const float* sw3 = (const float*)d_in[8];
    const float* sc3 = (const float*)d_in[9];
    const float* w1  = (const float*)d_in[10];
    const float* b1  = (const float*)d_in[11];
    const float* w2  = (const float*)d_in[12];
    const float* b2  = (const float*)d_in[13];

    float* ws  = (float*)d_ws;
    float* W1h = ws;              // packed: 25*17*8  = 3400 floats
    float* W2h = ws + 3400;       // packed: 16*22*8  = 2816 floats
    float* W3m = ws + 6216;       // fp32:   9*22*24  = 4752 floats
    float* bf  = ws + 10968;      // 10 (+pad)
    float* Wf  = ws + 11008;      // 34560
    float* o1  = ws + 45568;      // 256*12*12*12 = 442368
    float* o2  = ws + 487936;     // 256*144*4*4  = 589824
    float* x3  = ws + 1077760;    // 256*3456     = 884736
    float* out = (float*)d_out;

    prep_all<<<139, 256, 0, stream>>>(bw1, sw1, sc1, bw2, sw2, sc2,
                                      bw3, sw3, sc3, b1, w2, b2, w1,
                                      W1h, W2h, W3m, bf, Wf);

    const float h1 = 2.0f / 5.0f, h2 = 2.0f / 10.0f;
    // layer1: K=5, NINT=11, G=8,  N=12 packed, C=1,   28x28 -> pooled 12x12
    kan_conv_pool_h<5, 11, 8, 1, 28, 28, 12, 12>
        <<<576, 256, 0, stream>>>(x, W1h, o1, -3.0f * h1 - 1.0f, 1.0f / h1);
    // layer2: K=4, NINT=16, G=13, N=12 packed, C=12,  12x12 -> pooled 4x4
    kan_conv_pool_h<4, 16, 13, 12, 12, 12, 4, 4>
        <<<768, 256, 0, stream>>>(o1, W2h, o2, -3.0f * h2 - 1.0f, 1.0f / h2);
    // layer3: K=3, NINT=16, G=13, N=24 fp32, C=144, 4x4 -> pooled 1x1 (R5)
    kan_conv_pool<3, 16, 13, 24, 144, 4, 4, 1, 1>
        <<<576, 256, 0, stream>>>(o2, W3m, x3, -3.0f * h2 - 1.0f, 1.0f / h2);

    fc_kernel<<<640, 256, 0, stream>>>(x3, Wf, bf, out);
}

// Round 12
// 51.026 us; speedup vs baseline: 2.1834x; 1.5762x over previous
//
#include <hip/hip_runtime.h>
#include <math.h>

// ---------------------------------------------------------------------------
// SuperCKAN forward:
//   conv1 (k=5, grid5, n=12)  + pool -> (256,12,12,12)
//   conv2 (k=4, grid10, n=12) + pool -> (256,144,4,4)
//   conv3 (k=3, grid10, n=24) + pool -> (256,3456)
//   fc: x @ (w2@w1)^T + (b1@w2^T + b2) -> (256,10)
// All fp32.
//
// R11: launch-structure only; hot loop is EXACT R5 (best: 66.8us).
//  - f16 ABANDONED (R7/R9/R10 all regressed; unpack VALU > LDS savings).
//  - prep_all launch removed: conv blocks build their weight table directly
//    in LDS from raw bw/sw/scaler (same expressions/order -> bit-identical).
//  - Wf = w2@w1 blocks appended to conv1's grid (block-uniform role branch,
//    overlaps conv1).
//  - bf = b1@w2^T + b2 folded into fc's wave reduction (4 extra FMA/lane).
//  4 launches total: conv1+wf, conv2, conv3, fc.
// R4/R5 design kept: zero-padded tables [base][4 pad][G][4 pad], s clamped
// to [-1,NINT] (boundaries hit pad rows, no masking); float4 fc GEMV.
// ---------------------------------------------------------------------------

#define B_BATCH 256

// Weight LDS layout per layer: [K*K][R][N], R = G+9:
//   row 0: base (silu) w; rows 1..4: zero pad; rows 5..G+4: spline g=0..G-1
//   (scaler folded); rows G+5..G+8: zero pad.
// Spline rows for interval t (clamped to [-1, NINT]) are t+2+m, m=0..3.

// ---- fused KAN conv + 2x2 maxpool, sparse spline, in-LDS table build ------
// Thread quad (4 lanes, sub = 2x2 conv position) per pooled output position.
// Conv grid is EXACT (B_BATCH*C*POS*4 threads): no early return in conv role.
// WITH_WF: blocks [CONVBLKS, CONVBLKS+135) compute Wf = w2 @ w1 instead.
template <int K, int NINT, int G, int N, int C, int HIN, int WIN, int HP,
          int WP, bool WITH_WF>
__global__ __launch_bounds__(256, 4) void kan_conv_pool(
    const float* __restrict__ in,
    const float* __restrict__ bw, const float* __restrict__ sws,
    const float* __restrict__ scl,
    float* __restrict__ out, float g0, float invh,
    const float* __restrict__ w1, const float* __restrict__ w2,
    float* __restrict__ Wf)
{
    constexpr int R = G + 9;
    constexpr int POS = HP * WP;
    constexpr int WSZ = K * K * R * N;
    constexpr int KK = K * K;
    constexpr int CONVBLKS = B_BATCH * C * POS * 4 / 256;
    static_assert((N % 4) == 0, "alignment");

    if (WITH_WF && (int)blockIdx.x >= CONVBLKS) {
        // Wf = w2 @ w1 (10 x 3456); 135*256 = 34560 exact
        int gid = ((int)blockIdx.x - CONVBLKS) * 256 + threadIdx.x;
        int n = gid / 3456, m = gid % 3456;
        float s = 0.f;
        for (int j = 0; j < 256; ++j)
            s = fmaf(w2[n * 256 + j], w1[j * 3456 + m], s);
        Wf[n * 3456 + m] = s;
        return;                          // whole block exits (block-uniform)
    }

    // ---- build weight table in LDS from raw inputs (bit-identical to prep)
    __shared__ float sw[WSZ];
    for (int i = threadIdx.x; i < WSZ; i += 256) sw[i] = 0.f;
    __syncthreads();
    for (int e = threadIdx.x; e < N * KK; e += 256) {
        int n = e / KK, k = e % KK;
        float sc = scl[n * KK + k];
        sw[(k * R + 0) * N + n] = bw[n * KK + k];
        for (int g = 0; g < G; ++g)
            sw[(k * R + 5 + g) * N + n] = sws[(n * KK + k) * G + g] * sc;
    }
    __syncthreads();

    int tid = blockIdx.x * 256 + threadIdx.x;

    int sub = tid & 3;
    int rem = tid >> 2;
    int pos = rem % POS;
    int bc  = rem / POS;               // b*C + c
    int pi = pos / WP, pj = pos % WP;
    int p = 2 * pi + (sub >> 1);
    int q = 2 * pj + (sub & 1);

    const float* inp = in + bc * (HIN * WIN);

    float acc[N];
#pragma unroll
    for (int n = 0; n < N; ++n) acc[n] = 0.f;

#pragma unroll 1
    for (int dy = 0; dy < K; ++dy) {
#pragma unroll
        for (int dx = 0; dx < K; ++dx) {
            float v = inp[(p + dy) * WIN + (q + dx)];

            float s  = (v - g0) * invh;
            float sc = fminf(fmaxf(s, -1.0f), (float)NINT);  // sentinels hit pads
            float sf = floorf(sc);
            int   t  = (int)sf;
            float u  = sc - sf;                 // in [0,1]: coeffs stay finite
            float u2 = u * u, u3 = u2 * u;
            float um = 1.0f - u;
            float c0 = um * um * um * (1.0f / 6.0f);
            float c1 = (3.0f * u3 - 6.0f * u2 + 4.0f) * (1.0f / 6.0f);
            float c2 = (-3.0f * u3 + 3.0f * u2 + 3.0f * u + 1.0f) * (1.0f / 6.0f);
            float c3 = u3 * (1.0f / 6.0f);
            float sv = v / (1.0f + __expf(-v)); // silu

            const float* wk = sw + (dy * K + dx) * (R * N);  // base row (uniform)
            const float* wt = wk + (t + 2) * N;              // spline row block

#pragma unroll
            for (int n4 = 0; n4 < N / 4; ++n4) {
                float4 wb = ((const float4*)wk)[n4];
                float4 w0 = ((const float4*)(wt + 0 * N))[n4];
                float4 w1_ = ((const float4*)(wt + 1 * N))[n4];
                float4 w2_ = ((const float4*)(wt + 2 * N))[n4];
                float4 w3_ = ((const float4*)(wt + 3 * N))[n4];
                float a0 = acc[n4 * 4 + 0], a1 = acc[n4 * 4 + 1];
                float a2 = acc[n4 * 4 + 2], a3 = acc[n4 * 4 + 3];
                a0 = fmaf(sv, wb.x, a0); a1 = fmaf(sv, wb.y, a1);
                a2 = fmaf(sv, wb.z, a2); a3 = fmaf(sv, wb.w, a3);
                a0 = fmaf(c0, w0.x, a0); a1 = fmaf(c0, w0.y, a1);
                a2 = fmaf(c0, w0.z, a2); a3 = fmaf(c0, w0.w, a3);
                a0 = fmaf(c1, w1_.x, a0); a1 = fmaf(c1, w1_.y, a1);
                a2 = fmaf(c1, w1_.z, a2); a3 = fmaf(c1, w1_.w, a3);
                a0 = fmaf(c2, w2_.x, a0); a1 = fmaf(c2, w2_.y, a1);
                a2 = fmaf(c2, w2_.z, a2); a3 = fmaf(c2, w2_.w, a3);
                a0 = fmaf(c3, w3_.x, a0); a1 = fmaf(c3, w3_.y, a1);
                a2 = fmaf(c3, w3_.z, a2); a3 = fmaf(c3, w3_.w, a3);
                acc[n4 * 4 + 0] = a0; acc[n4 * 4 + 1] = a1;
                acc[n4 * 4 + 2] = a2; acc[n4 * 4 + 3] = a3;
            }
        }
    }

    // 2x2 maxpool across the lane quad
#pragma unroll
    for (int n = 0; n < N; ++n) {
        acc[n] = fmaxf(acc[n], __shfl_xor(acc[n], 1, 64));
        acc[n] = fmaxf(acc[n], __shfl_xor(acc[n], 2, 64));
    }

    // each of the 4 lanes writes N/4 channels
    constexpr int NPL = N / 4;
    int n0 = sub * NPL;
    float* op = out + bc * (N * POS) + pos;
#pragma unroll
    for (int i = 0; i < NPL; ++i)
        op[(n0 + i) * POS] = acc[n0 + i];
}

// ---- final GEMV: out = x3 @ Wf^T + (b1 @ w2^T + b2) -----------------------
// grid 2560 waves exact; bias fold merged into the same wave reduction.
__global__ __launch_bounds__(256) void fc_kernel(
    const float* __restrict__ x3, const float* __restrict__ Wf,
    const float* __restrict__ b1, const float* __restrict__ w2,
    const float* __restrict__ b2, float* __restrict__ out)
{
    int wid  = (blockIdx.x * 256 + threadIdx.x) >> 6;
    int lane = threadIdx.x & 63;
    int b = wid / 10, n = wid - b * 10;
    const float4* xr = (const float4*)(x3 + b * 3456);
    const float4* wr = (const float4*)(Wf + n * 3456);
    float s = 0.f;
#pragma unroll
    for (int i = 0; i < 13; ++i) {       // 13*64*4 = 3328 floats
        float4 a = xr[lane + i * 64];
        float4 w = wr[lane + i * 64];
        s = fmaf(a.x, w.x, s); s = fmaf(a.y, w.y, s);
        s = fmaf(a.z, w.z, s); s = fmaf(a.w, w.w, s);
    }
    const float* xs  = x3 + b * 3456 + 3328;  // remainder 128 floats
    const float* wsp = Wf + n * 3456 + 3328;
    s = fmaf(xs[lane], wsp[lane], s);
    s = fmaf(xs[lane + 64], wsp[lane + 64], s);
    // folded bias: b1 @ w2[n,:]
    const float* w2r = w2 + n * 256;
    s = fmaf(b1[lane],       w2r[lane],       s);
    s = fmaf(b1[lane + 64],  w2r[lane + 64],  s);
    s = fmaf(b1[lane + 128], w2r[lane + 128], s);
    s = fmaf(b1[lane + 192], w2r[lane + 192], s);
    for (int o = 32; o; o >>= 1) s += __shfl_down(s, o, 64);
    if (lane == 0) out[wid] = s + b2[n];
}

// ---------------------------------------------------------------------------
extern "C" void kernel_launch(void* const* d_in, const int* in_sizes, int n_in,
                              void* d_out, int out_size, void* d_ws, size_t ws_size,
                              hipStream_t stream)
{
    (void)in_sizes; (void)n_in; (void)out_size; (void)ws_size;
    const float* x   = (const float*)d_in[0];
    const float* bw1 = (const float*)d_in[1];
    const float* sw1 = (const float*)d_in[2];
    const float* sc1 = (const float*)d_in[3];
    const float* bw2 = (const float*)d_in[4];
    const float* sw2 = (const float*)d_in[5];
    const float* sc2 = (const float*)d_in[6];
    const float* bw3 = (const float*)d_in[7];
    const float* sw3 = (const float*)d_in[8];
    const float* sc3 = (const float*)d_in[9];
    const float* w1  = (const float*)d_in[10];
    const float* b1  = (const float*)d_in[11];
    const float* w2  = (const float*)d_in[12];
    const float* b2  = (const float*)d_in[13];

    float* ws  = (float*)d_ws;
    float* Wf  = ws;              // 34560
    float* o1  = ws + 34560;      // 256*12*12*12 = 442368
    float* o2  = ws + 476928;     // 256*144*4*4  = 589824
    float* x3  = ws + 1066752;    // 256*3456     = 884736
    float* out = (float*)d_out;

    const float h1 = 2.0f / 5.0f, h2 = 2.0f / 10.0f;
    // layer1 + Wf: conv blocks 576 + wf blocks 135 = 711
    kan_conv_pool<5, 11, 8, 12, 1, 28, 28, 12, 12, true>
        <<<711, 256, 0, stream>>>(x, bw1, sw1, sc1, o1,
                                  -3.0f * h1 - 1.0f, 1.0f / h1, w1, w2, Wf);
    // layer2: K=4, NINT=16, G=13, N=12, C=12, 12x12 -> pooled 4x4
    kan_conv_pool<4, 16, 13, 12, 12, 12, 12, 4, 4, false>
        <<<768, 256, 0, stream>>>(o1, bw2, sw2, sc2, o2,
                                  -3.0f * h2 - 1.0f, 1.0f / h2,
                                  nullptr, nullptr, nullptr);
    // layer3: K=3, NINT=16, G=13, N=24, C=144, 4x4 -> pooled 1x1
    kan_conv_pool<3, 16, 13, 24, 144, 4, 4, 1, 1, false>
        <<<576, 256, 0, stream>>>(o2, bw3, sw3, sc3, x3,
                                  -3.0f * h2 - 1.0f, 1.0f / h2,
                                  nullptr, nullptr, nullptr);
    // fc with folded bias
    fc_kernel<<<640, 256, 0, stream>>>(x3, Wf, b1, w2, b2, out);
}